// Round 7
// baseline (494.871 us; speedup 1.0000x reference)
//
#include <hip/hip_runtime.h>
#include <hip/hip_bf16.h>

#define NB 64     // batch
#define NI 2048   // input capsules
#define ND 16     // d_in
#define NJ 32     // output capsules
#define NE 32     // d_out
#define NIP (NI/2)  // i-pairs
#define NKC 128   // round-0 wsum grid kc dimension (128 chunks of 8 ip)
#define NSL NKC   // round-0 partial slices

typedef __attribute__((ext_vector_type(8))) short bfrag;   // 8 bf16 (4 VGPRs)
typedef __attribute__((ext_vector_type(4))) float f32x4;

// two floats -> packed bf16x2 (v_cvt_pk_bf16_f32 on gfx950), RNE
__device__ inline unsigned pk2bf(float a, float b) {
    __hip_bfloat162 h = __float22bfloat162_rn(make_float2(a, b));
    return *reinterpret_cast<unsigned*>(&h);
}

// add value rotated by N within each 16-lane DPP row (row_ror:N)
template <int N>
__device__ inline float rot16_add(float v) {
    int r = __builtin_amdgcn_mov_dpp(__float_as_int(v), 0x120 + N, 0xf, 0xf, false);
    return v + __int_as_float(r);
}

// unpack a dword of 2 bf16, scale by cc, repack (RNE)
__device__ inline unsigned scale_pair(unsigned u, float cc) {
    float f0 = __uint_as_float(u << 16);
    float f1 = __uint_as_float(u & 0xffff0000u);
    return pk2bf(f0 * cc, f1 * cc);
}

// ---------------------------------------------------------------------------
// convxT_k: x fp32 [NB][NI][ND] -> xT bf16 [NI][NB][ND].  (proven)
// ---------------------------------------------------------------------------
__global__ __launch_bounds__(256) void convxT_k(const float* __restrict__ x,
                                                short* __restrict__ xT)
{
    const int T = blockIdx.x * 256 + threadIdx.x;   // NI*NB = 131072
    const int i = T >> 6, b = T & 63;
    const float4* src = reinterpret_cast<const float4*>(
        x + ((size_t)b * NI + i) * ND);
    float4 a0 = src[0], a1 = src[1], a2 = src[2], a3 = src[3];
    bfrag lo, hi;
    unsigned* lu = reinterpret_cast<unsigned*>(&lo);
    unsigned* hu = reinterpret_cast<unsigned*>(&hi);
    lu[0] = pk2bf(a0.x, a0.y); lu[1] = pk2bf(a0.z, a0.w);
    lu[2] = pk2bf(a1.x, a1.y); lu[3] = pk2bf(a1.z, a1.w);
    hu[0] = pk2bf(a2.x, a2.y); hu[1] = pk2bf(a2.z, a2.w);
    hu[2] = pk2bf(a3.x, a3.y); hu[3] = pk2bf(a3.z, a3.w);
    short* dst = xT + ((size_t)i * NB + b) * ND;
    *reinterpret_cast<bfrag*>(dst)     = lo;
    *reinterpret_cast<bfrag*>(dst + 8) = hi;
}

// ---------------------------------------------------------------------------
// fwd_k: FUSED routing round (replaces lgsm + wsum for rounds 1,2).
// Rationale (r1-r6 PMC): four structurally different wsum variants all pin at
// ~2.1 TB/s effective; ILP and TLP fixes both null -> cut BYTES instead.
// lgsm already computes u_hat (U0/U1) in registers; softmax only needs all
// 32 j for an (i,b) -- which is exactly this block shape. So: per il,
//   phase1 (verbatim lgsm): logits L[j][b16] -> 2KB LDS tile (dbuf)
//   barrier; 16 threads softmax over j in-place (L -> c); barrier
//   phase2: recompute U0/U1 (2 MFMA, Wb reload = L1/L2-hot) and accumulate
//           s[b,j,e] += c * u_hat in fp32 VALU regs (s0/s1[jj][r]).
// Eliminates per round: 64MB second Wb read + 16MB c write + 16MB c read.
// Epilogue: one 64KB partial slice; rs2_k reduces over the 128 ic slices.
// Grid flat 512 = (bb=4 x ic=128), XCD co-location swizzle (lgsm's decode).
// ---------------------------------------------------------------------------
__global__ __launch_bounds__(512) void fwd_k(
    const short* __restrict__ xT,     // [NI][NB][ND] bf16
    const short* __restrict__ Wb,     // [NJ][NIP][NE][32] bf16
    const float* __restrict__ Oacc,   // [NB][NJ][NE]
    float* __restrict__ part)         // [4*128][NJ][16][32] = 32 MB
{
    const int l    = blockIdx.x;       // 0..511
    const int grp  = l >> 5;           // 16 groups
    const int bb   = (l >> 3) & 3;
    const int ic   = grp * 8 + (l & 7);
    const int b0   = bb * 16;
    const int i0   = ic * 16;
    const int t    = threadIdx.x;
    const int wv   = t >> 6;           // 0..7 -> j-set wv*4..wv*4+3
    const int ln   = t & 63;
    const int m    = ln & 15;
    const int quad = ln >> 4;

    __shared__ float lsm[2][NJ][16];   // [buf][j][b16]  2 x 2 KB

    // Hoist Oacc fragments for this wave's 4 j's (proven lgsm pattern).
    float O0[4][4], O1[4][4];
#pragma unroll
    for (int jj = 0; jj < 4; ++jj) {
        const int j = wv * 4 + jj;
#pragma unroll
        for (int r = 0; r < 4; ++r) {
            const int b = b0 + quad * 4 + r;
            O0[jj][r] = Oacc[((size_t)b * NJ + j) * NE + m];
            O1[jj][r] = Oacc[((size_t)b * NJ + j) * NE + 16 + m];
        }
    }

    const int  bA  = b0 + m;        // A-operand row (b) this lane supplies
    const bool act = quad < 2;      // quads 0,1 carry k=0..15 (d); 2,3 pad
    const int  d0  = quad * 8;

    float s0[4][4], s1[4][4];       // fp32 accum: [jj][r], e=m / e=m+16
#pragma unroll
    for (int jj = 0; jj < 4; ++jj)
#pragma unroll
        for (int r = 0; r < 4; ++r) { s0[jj][r] = 0.f; s1[jj][r] = 0.f; }

    for (int il = 0; il < 16; ++il) {
        const int buf = il & 1;
        const int i = i0 + il;
        const int ip = i >> 1, isel = i & 1;
        bfrag av = (bfrag)0;
        if (act) {
            av = *reinterpret_cast<const bfrag*>(
                xT + ((size_t)i * NB + bA) * ND + d0);
        }

        // ---- phase 1: logits (verbatim lgsm inner) -> lsm[buf] ----
#pragma unroll
        for (int jj = 0; jj < 4; ++jj) {
            const int j = wv * 4 + jj;
            bfrag bv0 = (bfrag)0, bv1 = (bfrag)0;
            if (act) {
                const short* wp = Wb + (((size_t)j * NIP + ip) * NE + m) * 32
                                     + isel * 16 + d0;
                bv0 = *reinterpret_cast<const bfrag*>(wp);
                bv1 = *reinterpret_cast<const bfrag*>(wp + 16 * 32);
            }
            f32x4 z = {0.f, 0.f, 0.f, 0.f};
            f32x4 U0 = __builtin_amdgcn_mfma_f32_16x16x32_bf16(av, bv0, z, 0, 0, 0);
            f32x4 U1 = __builtin_amdgcn_mfma_f32_16x16x32_bf16(av, bv1, z, 0, 0, 0);

            float v4[4];
#pragma unroll
            for (int r = 0; r < 4; ++r) {
                float v = fmaf(U0[r], O0[jj][r], U1[r] * O1[jj][r]);
                v = rot16_add<1>(v);
                v = rot16_add<2>(v);
                v = rot16_add<4>(v);
                v = rot16_add<8>(v);
                v4[r] = v;
            }
            if (m == 0) {
                *reinterpret_cast<float4*>(&lsm[buf][j][quad * 4]) =
                    make_float4(v4[0], v4[1], v4[2], v4[3]);
            }
        }
        __syncthreads();

        // ---- softmax over j, in place (threads 0..15, one b each) ----
        if (t < 16) {
            float mx = -1e30f;
#pragma unroll
            for (int jx = 0; jx < NJ; ++jx) mx = fmaxf(mx, lsm[buf][jx][t]);
            float sum = 0.f;
#pragma unroll
            for (int jx = 0; jx < NJ; ++jx) {
                const float e = __expf(lsm[buf][jx][t] - mx);
                lsm[buf][jx][t] = e;
                sum += e;
            }
            const float inv = 1.0f / sum;
#pragma unroll
            for (int jx = 0; jx < NJ; ++jx) lsm[buf][jx][t] *= inv;
        }
        __syncthreads();

        // ---- phase 2: recompute u_hat, accumulate s += c * u_hat ----
#pragma unroll
        for (int jj = 0; jj < 4; ++jj) {
            const int j = wv * 4 + jj;
            bfrag bv0 = (bfrag)0, bv1 = (bfrag)0;
            if (act) {
                const short* wp = Wb + (((size_t)j * NIP + ip) * NE + m) * 32
                                     + isel * 16 + d0;
                bv0 = *reinterpret_cast<const bfrag*>(wp);
                bv1 = *reinterpret_cast<const bfrag*>(wp + 16 * 32);
            }
            f32x4 z = {0.f, 0.f, 0.f, 0.f};
            f32x4 U0 = __builtin_amdgcn_mfma_f32_16x16x32_bf16(av, bv0, z, 0, 0, 0);
            f32x4 U1 = __builtin_amdgcn_mfma_f32_16x16x32_bf16(av, bv1, z, 0, 0, 0);
#pragma unroll
            for (int r = 0; r < 4; ++r) {
                const float cv = lsm[buf][j][quad * 4 + r];
                s0[jj][r] = fmaf(cv, U0[r], s0[jj][r]);
                s1[jj][r] = fmaf(cv, U1[r], s1[jj][r]);
            }
        }
        // next il writes lsm[buf^1]; lsm[buf] reused only after 2 barriers
    }

    // epilogue: slice sl2 = bb*128+ic, layout [sl2][j][b16][e]
    float* base = part + ((size_t)(bb * 128 + ic) * NJ) * 512;
#pragma unroll
    for (int jj = 0; jj < 4; ++jj) {
        const int j = wv * 4 + jj;
#pragma unroll
        for (int r = 0; r < 4; ++r) {
            float* p = base + (size_t)j * 512 + (quad * 4 + r) * 32 + m;
            p[0]  = s0[jj][r];
            p[16] = s1[jj][r];
        }
    }
}

// ---------------------------------------------------------------------------
// rs2_k: reduce fwd_k partials (128 ic slices per bb) + squash.
// Thread (b,j,e), e = lane&31 -> shuffle row-norm (rot16 + xor16), no LDS.
// mode 1: Oacc += squash(s);  mode 2: out = squash(s).
// ---------------------------------------------------------------------------
__global__ __launch_bounds__(512) void rs2_k(
    const float* __restrict__ part,      // [512][NJ][16][32]
    float* __restrict__ Oacc,            // [NB][NJ][NE]
    float* __restrict__ out,             // [NB][NJ][NE]
    int mode)
{
    const int G = blockIdx.x * 512 + threadIdx.x;   // 0..65535
    const int e = G & 31;
    const int j = (G >> 5) & 31;
    const int b = G >> 10;
    const int bb = b >> 4, bl = b & 15;

    const float* p = part + ((size_t)(bb * 128) * NJ + j) * 512 + bl * 32 + e;
    float sum = 0.f;
#pragma unroll 8
    for (int icx = 0; icx < 128; ++icx)
        sum += p[(size_t)icx * NJ * 512];

    float q = sum * sum;
    q = rot16_add<1>(q);
    q = rot16_add<2>(q);
    q = rot16_add<4>(q);
    q = rot16_add<8>(q);
    q += __shfl_xor(q, 16);

    const float scale = q / ((1.0f + q) * sqrtf(q + 1e-7f));
    const float o = scale * sum;
    const size_t off = ((size_t)b * NJ + j) * NE + e;
    if (mode == 2) out[off] = o;
    else           Oacc[off] += o;
}

// ---------------------------------------------------------------------------
// wsum_k<true>: round-0 only (uniform c=1/32), fuses W fp32 -> Wb bf16
// conversion. Verbatim from the passing round-6 kernel.
// ---------------------------------------------------------------------------

#define WS_LOAD(P, itv)                                                        \
    {   const int ip_ = ip0 + (itv);                                           \
        const int ia_ = ip_ * 2 + isel;                                        \
        {                                                                      \
            const float* wp_ = Wsrc + (((size_t)j * NI + ia_) * NE + m) * ND + d0; \
            P##w0 = *reinterpret_cast<const float4*>(wp_);                     \
            P##w1 = *reinterpret_cast<const float4*>(wp_ + 4);                 \
            P##w2 = *reinterpret_cast<const float4*>(wp_ + 16 * ND);           \
            P##w3 = *reinterpret_cast<const float4*>(wp_ + 16 * ND + 4);       \
        }                                                                      \
        const short* xp_ = xT + ((size_t)ia_ * NB + m) * ND + d0;              \
        P##x0 = *reinterpret_cast<const uint4*>(xp_);                          \
        P##x1 = *reinterpret_cast<const uint4*>(xp_ + 16 * ND);                \
        P##x2 = *reinterpret_cast<const uint4*>(xp_ + 32 * ND);                \
        P##x3 = *reinterpret_cast<const uint4*>(xp_ + 48 * ND);                \
    }

#define WS_MT(XV, A0, A1)                                                      \
    {   const float cc_ = 1.0f / NJ;                                           \
        bfrag av_;                                                             \
        unsigned* au_ = reinterpret_cast<unsigned*>(&av_);                     \
        au_[0] = scale_pair((XV).x, cc_); au_[1] = scale_pair((XV).y, cc_);    \
        au_[2] = scale_pair((XV).z, cc_); au_[3] = scale_pair((XV).w, cc_);    \
        A0 = __builtin_amdgcn_mfma_f32_16x16x32_bf16(av_, bv0_, A0, 0, 0, 0);  \
        A1 = __builtin_amdgcn_mfma_f32_16x16x32_bf16(av_, bv1_, A1, 0, 0, 0);  \
    }

#define WS_COMPUTE(P, itv)                                                     \
    {   bfrag bv0_, bv1_;                                                      \
        {                                                                      \
            unsigned* b0_ = reinterpret_cast<unsigned*>(&bv0_);                \
            unsigned* b1_ = reinterpret_cast<unsigned*>(&bv1_);                \
            b0_[0] = pk2bf(P##w0.x, P##w0.y); b0_[1] = pk2bf(P##w0.z, P##w0.w);\
            b0_[2] = pk2bf(P##w1.x, P##w1.y); b0_[3] = pk2bf(P##w1.z, P##w1.w);\
            b1_[0] = pk2bf(P##w2.x, P##w2.y); b1_[1] = pk2bf(P##w2.z, P##w2.w);\
            b1_[2] = pk2bf(P##w3.x, P##w3.y); b1_[3] = pk2bf(P##w3.z, P##w3.w);\
            short* wd_ = Wb + (((size_t)j * NIP + (ip0 + (itv))) * NE + m) * 32 + quad * 8; \
            *reinterpret_cast<bfrag*>(wd_)       = bv0_;                       \
            *reinterpret_cast<bfrag*>(wd_ + 512) = bv1_;                       \
        }                                                                      \
        WS_MT(P##x0, a00, a01)                                                 \
        WS_MT(P##x1, a10, a11)                                                 \
        WS_MT(P##x2, a20, a21)                                                 \
        WS_MT(P##x3, a30, a31)                                                 \
    }

__global__ __launch_bounds__(128) void wsum_k(
    const float* __restrict__ Wsrc,   // [NJ][NI][NE][ND] fp32
    const short* __restrict__ xT,     // [NI][NB][ND] bf16
    short* __restrict__ Wb,           // [NJ][NIP][NE][32] bf16 (out)
    float* __restrict__ partial)      // [NSL][NJ][2048]
{
    const int l    = blockIdx.x;       // 0..4095
    const int x    = l & 7;            // XCD slot
    const int r    = l >> 3;           // 0..511
    const int j    = r & 31;
    const int kc   = x * 16 + (r >> 5);
    const int t    = threadIdx.x;      // 0..127
    const int wv   = t >> 6;           // 0..1
    const int ln   = t & 63;
    const int m    = ln & 15;
    const int quad = ln >> 4;
    const int isel = quad >> 1;
    const int d0   = (quad & 1) * 8;
    const int ip0  = kc * 8 + wv * 4;

    __shared__ float red[2048];

    f32x4 a00 = {0.f,0.f,0.f,0.f}, a01 = {0.f,0.f,0.f,0.f};
    f32x4 a10 = {0.f,0.f,0.f,0.f}, a11 = {0.f,0.f,0.f,0.f};
    f32x4 a20 = {0.f,0.f,0.f,0.f}, a21 = {0.f,0.f,0.f,0.f};
    f32x4 a30 = {0.f,0.f,0.f,0.f}, a31 = {0.f,0.f,0.f,0.f};

    float4 Aw0, Aw1, Aw2, Aw3, Bw0, Bw1, Bw2, Bw3;
    uint4  Ax0, Ax1, Ax2, Ax3, Bx0, Bx1, Bx2, Bx3;

    WS_LOAD(A, 0)
    WS_LOAD(B, 1)
    WS_COMPUTE(A, 0)
    WS_LOAD(A, 2)
    WS_COMPUTE(B, 1)
    WS_LOAD(B, 3)
    WS_COMPUTE(A, 2)
    WS_COMPUTE(B, 3)

    if (wv == 1) {
        *reinterpret_cast<f32x4*>(red + 0 * 256 + ln * 4) = a00;
        *reinterpret_cast<f32x4*>(red + 1 * 256 + ln * 4) = a01;
        *reinterpret_cast<f32x4*>(red + 2 * 256 + ln * 4) = a10;
        *reinterpret_cast<f32x4*>(red + 3 * 256 + ln * 4) = a11;
        *reinterpret_cast<f32x4*>(red + 4 * 256 + ln * 4) = a20;
        *reinterpret_cast<f32x4*>(red + 5 * 256 + ln * 4) = a21;
        *reinterpret_cast<f32x4*>(red + 6 * 256 + ln * 4) = a30;
        *reinterpret_cast<f32x4*>(red + 7 * 256 + ln * 4) = a31;
    }
    __syncthreads();

    if (wv == 0) {
        float* pb = partial + ((size_t)kc * NJ + j) * 2048;
        a00 += *reinterpret_cast<const f32x4*>(red + 0 * 256 + ln * 4);
        a01 += *reinterpret_cast<const f32x4*>(red + 1 * 256 + ln * 4);
        a10 += *reinterpret_cast<const f32x4*>(red + 2 * 256 + ln * 4);
        a11 += *reinterpret_cast<const f32x4*>(red + 3 * 256 + ln * 4);
        a20 += *reinterpret_cast<const f32x4*>(red + 4 * 256 + ln * 4);
        a21 += *reinterpret_cast<const f32x4*>(red + 5 * 256 + ln * 4);
        a30 += *reinterpret_cast<const f32x4*>(red + 6 * 256 + ln * 4);
        a31 += *reinterpret_cast<const f32x4*>(red + 7 * 256 + ln * 4);
        *reinterpret_cast<f32x4*>(pb + 0 * 256 + ln * 4) = a00;
        *reinterpret_cast<f32x4*>(pb + 1 * 256 + ln * 4) = a01;
        *reinterpret_cast<f32x4*>(pb + 2 * 256 + ln * 4) = a10;
        *reinterpret_cast<f32x4*>(pb + 3 * 256 + ln * 4) = a11;
        *reinterpret_cast<f32x4*>(pb + 4 * 256 + ln * 4) = a20;
        *reinterpret_cast<f32x4*>(pb + 5 * 256 + ln * 4) = a21;
        *reinterpret_cast<f32x4*>(pb + 6 * 256 + ln * 4) = a30;
        *reinterpret_cast<f32x4*>(pb + 7 * 256 + ln * 4) = a31;
    }
}

// ---------------------------------------------------------------------------
// rs_k: round-0 reduce (wsum partial layout) + squash. Verbatim from r6.
// mode 0: Oacc = squash(s).
// ---------------------------------------------------------------------------
__global__ __launch_bounds__(512) void rs_k(
    const float* __restrict__ partial,   // [NSL][NJ][2048]
    float* __restrict__ Oacc,            // [NB][NJ][NE]
    float* __restrict__ out,             // [NB][NJ][NE]
    int mode)
{
    const int G    = blockIdx.x * 512 + threadIdx.x;   // 0..65535
    const int j    = G >> 11;
    const int g    = G & 2047;
    const int group = g >> 8;           // 0..7 = mt*2+nt
    const int mt   = group >> 1;
    const int nt   = group & 1;
    const int lnn  = (g >> 2) & 63;
    const int m    = lnn & 15;
    const int quad = lnn >> 4;
    const int r    = g & 3;
    const int b    = mt * 16 + quad * 4 + r;
    const int e    = nt * 16 + m;

    float sum = 0.f;
#pragma unroll 8
    for (int sl = 0; sl < NSL; ++sl)
        sum += partial[((size_t)sl * NJ + j) * 2048 + g];

    __shared__ float lds[512];
    const int row = quad * 4 + r;        // 0..15
    lds[row * 32 + e] = sum;
    __syncthreads();
    const float* rp = &lds[row * 32];
    float p = 0.f;
#pragma unroll
    for (int ee = 0; ee < 32; ++ee) p = fmaf(rp[ee], rp[ee], p);

    const float scale = p / ((1.0f + p) * sqrtf(p + 1e-7f));
    const float o = scale * sum;
    const size_t off = ((size_t)b * NJ + j) * NE + e;
    if (mode == 2)      out[off]  = o;
    else if (mode == 1) Oacc[off] += o;
    else                Oacc[off] = o;
}

extern "C" void kernel_launch(void* const* d_in, const int* in_sizes, int n_in,
                              void* d_out, int out_size, void* d_ws, size_t ws_size,
                              hipStream_t stream)
{
    (void)in_sizes; (void)n_in; (void)out_size; (void)ws_size;
    const float* x = (const float*)d_in[0];   // [64][2048][16]
    const float* W = (const float*)d_in[1];   // [32][2048][32][16]
    float* out = (float*)d_out;               // [64][32][32]

    // ws layout (~104 MB of 512 MB). part is shared by the round-0 wsum
    // layout and the fwd_k slice layout (sequential use, both 32 MB).
    float* Oacc = (float*)d_ws;                        // 64K floats  (256 KB)
    float* part = Oacc + NB * NJ * NE;                 // 32 MB
    short* Wb   = (short*)(part + (size_t)NSL * NJ * 2048);  // 64 MB
    short* xT   = Wb + (size_t)NJ * NIP * NE * 32;           // 8 MB

    convxT_k<<<(NI * NB) / 256, 256, 0, stream>>>(x, xT);

    // round 0: uniform c = 1/32; converts W -> Wb inline
    wsum_k<<<NJ * NKC, 128, 0, stream>>>(W, xT, Wb, part);
    rs_k<<<65536 / 512, 512, 0, stream>>>(part, Oacc, out, 0);

    // round 1 (fused logits+softmax+weighted-sum)
    fwd_k<<<512, 512, 0, stream>>>(xT, Wb, Oacc, part);
    rs2_k<<<65536 / 512, 512, 0, stream>>>(part, Oacc, out, 1);

    // round 2
    fwd_k<<<512, 512, 0, stream>>>(xT, Wb, Oacc, part);
    rs2_k<<<65536 / 512, 512, 0, stream>>>(part, Oacc, out, 2);
}

// Round 8
// 359.035 us; speedup vs baseline: 1.3783x; 1.3783x over previous
//
#include <hip/hip_runtime.h>
#include <hip/hip_bf16.h>

#define NB 64     // batch
#define NI 2048   // input capsules
#define ND 16     // d_in
#define NJ 32     // output capsules
#define NE 32     // d_out
#define NIP (NI/2)  // i-pairs
#define NKC 64    // round-0 wsum grid kc dimension (64 chunks of 16 ip)
#define NSL NKC   // round-0 partial slices

typedef __attribute__((ext_vector_type(8))) short bfrag;   // 8 bf16 (4 VGPRs)
typedef __attribute__((ext_vector_type(4))) float f32x4;

// two floats -> packed bf16x2 (v_cvt_pk_bf16_f32 on gfx950), RNE
__device__ inline unsigned pk2bf(float a, float b) {
    __hip_bfloat162 h = __float22bfloat162_rn(make_float2(a, b));
    return *reinterpret_cast<unsigned*>(&h);
}

// add value rotated by N within each 16-lane DPP row (row_ror:N)
template <int N>
__device__ inline float rot16_add(float v) {
    int r = __builtin_amdgcn_mov_dpp(__float_as_int(v), 0x120 + N, 0xf, 0xf, false);
    return v + __int_as_float(r);
}

// unpack a dword of 2 bf16, scale by cc, repack (RNE)
__device__ inline unsigned scale_pair(unsigned u, float cc) {
    float f0 = __uint_as_float(u << 16);
    float f1 = __uint_as_float(u & 0xffff0000u);
    return pk2bf(f0 * cc, f1 * cc);
}

// ---------------------------------------------------------------------------
// convxT_k: x fp32 [NB][NI][ND] -> xT bf16 [NI][NB][ND].  (proven)
// ---------------------------------------------------------------------------
__global__ __launch_bounds__(256) void convxT_k(const float* __restrict__ x,
                                                short* __restrict__ xT)
{
    const int T = blockIdx.x * 256 + threadIdx.x;   // NI*NB = 131072
    const int i = T >> 6, b = T & 63;
    const float4* src = reinterpret_cast<const float4*>(
        x + ((size_t)b * NI + i) * ND);
    float4 a0 = src[0], a1 = src[1], a2 = src[2], a3 = src[3];
    bfrag lo, hi;
    unsigned* lu = reinterpret_cast<unsigned*>(&lo);
    unsigned* hu = reinterpret_cast<unsigned*>(&hi);
    lu[0] = pk2bf(a0.x, a0.y); lu[1] = pk2bf(a0.z, a0.w);
    lu[2] = pk2bf(a1.x, a1.y); lu[3] = pk2bf(a1.z, a1.w);
    hu[0] = pk2bf(a2.x, a2.y); hu[1] = pk2bf(a2.z, a2.w);
    hu[2] = pk2bf(a3.x, a3.y); hu[3] = pk2bf(a3.z, a3.w);
    short* dst = xT + ((size_t)i * NB + b) * ND;
    *reinterpret_cast<bfrag*>(dst)     = lo;
    *reinterpret_cast<bfrag*>(dst + 8) = hi;
}

// ---------------------------------------------------------------------------
// fwd_k v2: fused routing round, BATCHED phases (fix for r7's 132us:
// 32 barriers + 16-thread serial softmax + per-il chains -> 2 barriers,
// 256-thread softmax, cross-il pipelining).
//   phase1 = lgsm's proven loop over ALL il -> lsm[16][32][16] (32 KB)
//   barrier; softmax: 256 threads, one (il,b) row each; barrier
//   phase2 = wsum's proven math: A-frag = c*x (scale_pair), MFMA-accumulate
//            s[b,j,e] directly (no U recompute into scalars).
// Traffic per round (proven by r7 PMC): ~37 MB fetch + 33 MB write.
// Grid flat 512 = (bb=4 x ic=128) with XCD co-location swizzle.
// ---------------------------------------------------------------------------
__global__ __launch_bounds__(512) void fwd_k(
    const short* __restrict__ xT,     // [NI][NB][ND] bf16
    const short* __restrict__ Wb,     // [NJ][NIP][NE][32] bf16
    const float* __restrict__ Oacc,   // [NB][NJ][NE]
    float* __restrict__ part)         // [512][NJ][16][32] = 32 MB
{
    const int l    = blockIdx.x;       // 0..511
    const int grp  = l >> 5;           // 16 groups
    const int bb   = (l >> 3) & 3;
    const int ic   = grp * 8 + (l & 7);
    const int b0   = bb * 16;
    const int i0   = ic * 16;
    const int t    = threadIdx.x;
    const int wv   = t >> 6;           // 0..7 -> j-set wv*4..wv*4+3
    const int ln   = t & 63;
    const int m    = ln & 15;
    const int quad = ln >> 4;

    __shared__ float lsm[16][NJ][16];  // [il][j][b16]  32 KB

    // Hoist Oacc fragments for this wave's 4 j's (proven lgsm pattern).
    float O0[4][4], O1[4][4];
#pragma unroll
    for (int jj = 0; jj < 4; ++jj) {
        const int j = wv * 4 + jj;
#pragma unroll
        for (int r = 0; r < 4; ++r) {
            const int b = b0 + quad * 4 + r;
            O0[jj][r] = Oacc[((size_t)b * NJ + j) * NE + m];
            O1[jj][r] = Oacc[((size_t)b * NJ + j) * NE + 16 + m];
        }
    }

    const int  bA  = b0 + m;        // A-operand row (b) this lane supplies
    const bool act = quad < 2;      // quads 0,1 carry k=0..15 (d); 2,3 pad
    const int  d0  = quad * 8;

    // ---- phase 1: ALL logits (no barriers inside -> cross-il ILP) ----
    for (int il = 0; il < 16; ++il) {
        const int i = i0 + il;
        const int ip = i >> 1, isel = i & 1;
        bfrag av = (bfrag)0;
        if (act) {
            av = *reinterpret_cast<const bfrag*>(
                xT + ((size_t)i * NB + bA) * ND + d0);
        }
#pragma unroll
        for (int jj = 0; jj < 4; ++jj) {
            const int j = wv * 4 + jj;
            bfrag bv0 = (bfrag)0, bv1 = (bfrag)0;
            if (act) {
                const short* wp = Wb + (((size_t)j * NIP + ip) * NE + m) * 32
                                     + isel * 16 + d0;
                bv0 = *reinterpret_cast<const bfrag*>(wp);
                bv1 = *reinterpret_cast<const bfrag*>(wp + 16 * 32);
            }
            f32x4 z = {0.f, 0.f, 0.f, 0.f};
            f32x4 U0 = __builtin_amdgcn_mfma_f32_16x16x32_bf16(av, bv0, z, 0, 0, 0);
            f32x4 U1 = __builtin_amdgcn_mfma_f32_16x16x32_bf16(av, bv1, z, 0, 0, 0);

            float v4[4];
#pragma unroll
            for (int r = 0; r < 4; ++r) {
                float v = fmaf(U0[r], O0[jj][r], U1[r] * O1[jj][r]);
                v = rot16_add<1>(v);
                v = rot16_add<2>(v);
                v = rot16_add<4>(v);
                v = rot16_add<8>(v);
                v4[r] = v;
            }
            if (m == 0) {
                *reinterpret_cast<float4*>(&lsm[il][j][quad * 4]) =
                    make_float4(v4[0], v4[1], v4[2], v4[3]);
            }
        }
    }
    __syncthreads();

    // ---- softmax over j: 256 threads, one (il,b) row each ----
    if (t < 256) {
        const int il = t >> 4, b = t & 15;
        float mx = -1e30f;
#pragma unroll
        for (int jx = 0; jx < NJ; ++jx) mx = fmaxf(mx, lsm[il][jx][b]);
        float sum = 0.f;
#pragma unroll
        for (int jx = 0; jx < NJ; ++jx) {
            const float e = __expf(lsm[il][jx][b] - mx);
            lsm[il][jx][b] = e;
            sum += e;
        }
        const float inv = 1.0f / sum;
#pragma unroll
        for (int jx = 0; jx < NJ; ++jx) lsm[il][jx][b] *= inv;
    }
    __syncthreads();

    // ---- phase 2: s[b,j,e] += c * u_hat via c-scaled A (wsum math) ----
    f32x4 acc0[4] = {{0.f,0.f,0.f,0.f},{0.f,0.f,0.f,0.f},
                     {0.f,0.f,0.f,0.f},{0.f,0.f,0.f,0.f}};
    f32x4 acc1[4] = {{0.f,0.f,0.f,0.f},{0.f,0.f,0.f,0.f},
                     {0.f,0.f,0.f,0.f},{0.f,0.f,0.f,0.f}};
    for (int il = 0; il < 16; ++il) {
        const int i = i0 + il;
        const int ip = i >> 1, isel = i & 1;
        uint4 xr = {0u, 0u, 0u, 0u};
        if (act) {
            xr = *reinterpret_cast<const uint4*>(
                xT + ((size_t)i * NB + bA) * ND + d0);
        }
#pragma unroll
        for (int jj = 0; jj < 4; ++jj) {
            const int j = wv * 4 + jj;
            const float cv = lsm[il][j][m];    // c[j][i][b=bA] (broadcast)
            bfrag av2;
            unsigned* au = reinterpret_cast<unsigned*>(&av2);
            au[0] = scale_pair(xr.x, cv);
            au[1] = scale_pair(xr.y, cv);
            au[2] = scale_pair(xr.z, cv);
            au[3] = scale_pair(xr.w, cv);
            bfrag bv0 = (bfrag)0, bv1 = (bfrag)0;
            if (act) {
                const short* wp = Wb + (((size_t)j * NIP + ip) * NE + m) * 32
                                     + isel * 16 + d0;
                bv0 = *reinterpret_cast<const bfrag*>(wp);
                bv1 = *reinterpret_cast<const bfrag*>(wp + 16 * 32);
            }
            acc0[jj] = __builtin_amdgcn_mfma_f32_16x16x32_bf16(av2, bv0, acc0[jj], 0, 0, 0);
            acc1[jj] = __builtin_amdgcn_mfma_f32_16x16x32_bf16(av2, bv1, acc1[jj], 0, 0, 0);
        }
    }

    // epilogue: slice sl2 = bb*128+ic, layout [sl2][j][b16][e32]
    float* base = part + ((size_t)(bb * 128 + ic) * NJ) * 512;
#pragma unroll
    for (int jj = 0; jj < 4; ++jj) {
        const int j = wv * 4 + jj;
#pragma unroll
        for (int r = 0; r < 4; ++r) {
            float* p = base + (size_t)j * 512 + (quad * 4 + r) * 32 + m;
            p[0]  = acc0[jj][r];
            p[16] = acc1[jj][r];
        }
    }
}

// ---------------------------------------------------------------------------
// rs2_k v2: reduce fwd partials + squash. Fix for the hidden ~55us/dispatch:
// r7 had 65536 threads (4 waves/CU) x 128 serial 64KB-stride loads. Now
// 4-way slice split (262144 threads = 16 waves/CU, 32 independent loads
// each) + LDS combine + shuffle e-norm.
// ---------------------------------------------------------------------------
__global__ __launch_bounds__(512) void rs2_k(
    const float* __restrict__ part,      // [512][NJ][16][32]
    float* __restrict__ Oacc,            // [NB][NJ][NE]
    float* __restrict__ out,             // [NB][NJ][NE]
    int mode)
{
    const int G2 = blockIdx.x * 512 + threadIdx.x;  // 0..262143
    const int row = G2 >> 2;                        // (b,j,e)
    const int q   = G2 & 3;                         // slice quarter
    const int e = row & 31, j = (row >> 5) & 31, b = row >> 10;
    const int bb = b >> 4, bl = b & 15;

    const float* p = part + ((size_t)(bb * 128 + q * 32) * NJ + j) * 512
                          + bl * 32 + e;
    float sum = 0.f;
#pragma unroll 8
    for (int s = 0; s < 32; ++s)
        sum += p[(size_t)s * NJ * 512];

    __shared__ float lds[512];
    lds[threadIdx.x] = sum;
    __syncthreads();

    if (threadIdx.x < 128) {
        const int t4 = threadIdx.x * 4;
        const float s = lds[t4] + lds[t4 + 1] + lds[t4 + 2] + lds[t4 + 3];
        const int row2 = blockIdx.x * 128 + threadIdx.x;
        const int e2 = row2 & 31, j2 = (row2 >> 5) & 31, b2 = row2 >> 10;
        float qq = s * s;
        qq += __shfl_xor(qq, 1);
        qq += __shfl_xor(qq, 2);
        qq += __shfl_xor(qq, 4);
        qq += __shfl_xor(qq, 8);
        qq += __shfl_xor(qq, 16);
        const float scale = qq / ((1.0f + qq) * sqrtf(qq + 1e-7f));
        const float o = scale * s;
        const size_t off = ((size_t)b2 * NJ + j2) * NE + e2;
        if (mode == 2) out[off] = o;
        else           Oacc[off] += o;
    }
}

// ---------------------------------------------------------------------------
// wsum_k: round-0 only (uniform c=1/32), fuses W fp32 -> Wb bf16 conversion.
// This is the r3-PROVEN 8-stage named-variable pipeline (NKC=64), R0 branch
// specialized. XCD-grouped kc keeps per-XCD xT footprint L2-resident.
// ---------------------------------------------------------------------------

#define WS_LOAD(P, itv)                                                        \
    {   const int ip_ = ip0 + (itv);                                           \
        const int ia_ = ip_ * 2 + isel;                                        \
        {                                                                      \
            const float* wp_ = Wsrc + (((size_t)j * NI + ia_) * NE + m) * ND + d0; \
            P##w0 = *reinterpret_cast<const float4*>(wp_);                     \
            P##w1 = *reinterpret_cast<const float4*>(wp_ + 4);                 \
            P##w2 = *reinterpret_cast<const float4*>(wp_ + 16 * ND);           \
            P##w3 = *reinterpret_cast<const float4*>(wp_ + 16 * ND + 4);       \
        }                                                                      \
        const short* xp_ = xT + ((size_t)ia_ * NB + m) * ND + d0;              \
        P##x0 = *reinterpret_cast<const uint4*>(xp_);                          \
        P##x1 = *reinterpret_cast<const uint4*>(xp_ + 16 * ND);                \
        P##x2 = *reinterpret_cast<const uint4*>(xp_ + 32 * ND);                \
        P##x3 = *reinterpret_cast<const uint4*>(xp_ + 48 * ND);                \
    }

#define WS_MT(XV, A0, A1)                                                      \
    {   const float cc_ = 1.0f / NJ;                                           \
        bfrag av_;                                                             \
        unsigned* au_ = reinterpret_cast<unsigned*>(&av_);                     \
        au_[0] = scale_pair((XV).x, cc_); au_[1] = scale_pair((XV).y, cc_);    \
        au_[2] = scale_pair((XV).z, cc_); au_[3] = scale_pair((XV).w, cc_);    \
        A0 = __builtin_amdgcn_mfma_f32_16x16x32_bf16(av_, bv0_, A0, 0, 0, 0);  \
        A1 = __builtin_amdgcn_mfma_f32_16x16x32_bf16(av_, bv1_, A1, 0, 0, 0);  \
    }

#define WS_COMPUTE(P, itv)                                                     \
    {   bfrag bv0_, bv1_;                                                      \
        {                                                                      \
            unsigned* b0_ = reinterpret_cast<unsigned*>(&bv0_);                \
            unsigned* b1_ = reinterpret_cast<unsigned*>(&bv1_);                \
            b0_[0] = pk2bf(P##w0.x, P##w0.y); b0_[1] = pk2bf(P##w0.z, P##w0.w);\
            b0_[2] = pk2bf(P##w1.x, P##w1.y); b0_[3] = pk2bf(P##w1.z, P##w1.w);\
            b1_[0] = pk2bf(P##w2.x, P##w2.y); b1_[1] = pk2bf(P##w2.z, P##w2.w);\
            b1_[2] = pk2bf(P##w3.x, P##w3.y); b1_[3] = pk2bf(P##w3.z, P##w3.w);\
            short* wd_ = Wb + (((size_t)j * NIP + (ip0 + (itv))) * NE + m) * 32 + quad * 8; \
            *reinterpret_cast<bfrag*>(wd_)       = bv0_;                       \
            *reinterpret_cast<bfrag*>(wd_ + 512) = bv1_;                       \
        }                                                                      \
        WS_MT(P##x0, a00, a01)                                                 \
        WS_MT(P##x1, a10, a11)                                                 \
        WS_MT(P##x2, a20, a21)                                                 \
        WS_MT(P##x3, a30, a31)                                                 \
    }

__global__ __launch_bounds__(128) void wsum_k(
    const float* __restrict__ Wsrc,   // [NJ][NI][NE][ND] fp32
    const short* __restrict__ xT,     // [NI][NB][ND] bf16
    short* __restrict__ Wb,           // [NJ][NIP][NE][32] bf16 (out)
    float* __restrict__ partial)      // [NSL][NJ][2048]
{
    const int l    = blockIdx.x;       // 0..2047
    const int x    = l & 7;            // XCD slot
    const int r    = l >> 3;           // 0..255
    const int j    = r & 31;
    const int kc   = x * 8 + (r >> 5); // 0..63
    const int t    = threadIdx.x;      // 0..127
    const int wv   = t >> 6;           // 0..1
    const int ln   = t & 63;
    const int m    = ln & 15;
    const int quad = ln >> 4;
    const int isel = quad >> 1;
    const int d0   = (quad & 1) * 8;
    const int ip0  = kc * 16 + wv * 8;

    __shared__ float red[2][2048];     // 16 KB

    f32x4 a00 = {0.f,0.f,0.f,0.f}, a01 = {0.f,0.f,0.f,0.f};
    f32x4 a10 = {0.f,0.f,0.f,0.f}, a11 = {0.f,0.f,0.f,0.f};
    f32x4 a20 = {0.f,0.f,0.f,0.f}, a21 = {0.f,0.f,0.f,0.f};
    f32x4 a30 = {0.f,0.f,0.f,0.f}, a31 = {0.f,0.f,0.f,0.f};

    float4 Aw0, Aw1, Aw2, Aw3, Bw0, Bw1, Bw2, Bw3;
    uint4  Ax0, Ax1, Ax2, Ax3, Bx0, Bx1, Bx2, Bx3;

    WS_LOAD(A, 0)
    WS_LOAD(B, 1)
    WS_COMPUTE(A, 0)
    WS_LOAD(A, 2)
    WS_COMPUTE(B, 1)
    WS_LOAD(B, 3)
    WS_COMPUTE(A, 2)
    WS_LOAD(A, 4)
    WS_COMPUTE(B, 3)
    WS_LOAD(B, 5)
    WS_COMPUTE(A, 4)
    WS_LOAD(A, 6)
    WS_COMPUTE(B, 5)
    WS_LOAD(B, 7)
    WS_COMPUTE(A, 6)
    WS_COMPUTE(B, 7)

    float* rb = &red[wv][0];
    *reinterpret_cast<f32x4*>(rb + 0 * 256 + ln * 4) = a00;
    *reinterpret_cast<f32x4*>(rb + 1 * 256 + ln * 4) = a01;
    *reinterpret_cast<f32x4*>(rb + 2 * 256 + ln * 4) = a10;
    *reinterpret_cast<f32x4*>(rb + 3 * 256 + ln * 4) = a11;
    *reinterpret_cast<f32x4*>(rb + 4 * 256 + ln * 4) = a20;
    *reinterpret_cast<f32x4*>(rb + 5 * 256 + ln * 4) = a21;
    *reinterpret_cast<f32x4*>(rb + 6 * 256 + ln * 4) = a30;
    *reinterpret_cast<f32x4*>(rb + 7 * 256 + ln * 4) = a31;
    __syncthreads();

    float* pb = partial + ((size_t)kc * NJ + j) * 2048;
#pragma unroll
    for (int k = 0; k < 4; ++k) {
        const int g = k * 512 + t * 4;
        f32x4 s = *reinterpret_cast<const f32x4*>(&red[0][g]);
        s += *reinterpret_cast<const f32x4*>(&red[1][g]);
        *reinterpret_cast<f32x4*>(pb + g) = s;
    }
}

// ---------------------------------------------------------------------------
// rs_k: round-0 reduce (wsum flat layout, NSL=64) + squash. mode 0 only.
// ---------------------------------------------------------------------------
__global__ __launch_bounds__(512) void rs_k(
    const float* __restrict__ partial,   // [NSL][NJ][2048]
    float* __restrict__ Oacc,            // [NB][NJ][NE]
    float* __restrict__ out,             // [NB][NJ][NE]
    int mode)
{
    const int G    = blockIdx.x * 512 + threadIdx.x;   // 0..65535
    const int j    = G >> 11;
    const int g    = G & 2047;
    const int group = g >> 8;           // 0..7 = mt*2+nt
    const int mt   = group >> 1;
    const int nt   = group & 1;
    const int lnn  = (g >> 2) & 63;
    const int m    = lnn & 15;
    const int quad = lnn >> 4;
    const int r    = g & 3;
    const int b    = mt * 16 + quad * 4 + r;
    const int e    = nt * 16 + m;

    float sum = 0.f;
#pragma unroll 8
    for (int sl = 0; sl < NSL; ++sl)
        sum += partial[((size_t)sl * NJ + j) * 2048 + g];

    __shared__ float lds[512];
    const int row = quad * 4 + r;        // 0..15
    lds[row * 32 + e] = sum;
    __syncthreads();
    const float* rp = &lds[row * 32];
    float p = 0.f;
#pragma unroll
    for (int ee = 0; ee < 32; ++ee) p = fmaf(rp[ee], rp[ee], p);

    const float scale = p / ((1.0f + p) * sqrtf(p + 1e-7f));
    const float o = scale * sum;
    const size_t off = ((size_t)b * NJ + j) * NE + e;
    if (mode == 2)      out[off]  = o;
    else if (mode == 1) Oacc[off] += o;
    else                Oacc[off] = o;
}

extern "C" void kernel_launch(void* const* d_in, const int* in_sizes, int n_in,
                              void* d_out, int out_size, void* d_ws, size_t ws_size,
                              hipStream_t stream)
{
    (void)in_sizes; (void)n_in; (void)out_size; (void)ws_size;
    const float* x = (const float*)d_in[0];   // [64][2048][16]
    const float* W = (const float*)d_in[1];   // [32][2048][32][16]
    float* out = (float*)d_out;               // [64][32][32]

    // ws layout (~104 MB of 512 MB). part region (32 MB) is shared by the
    // round-0 flat layout (16 MB) and fwd's slice layout (sequential use).
    float* Oacc = (float*)d_ws;                        // 256 KB
    float* part = Oacc + NB * NJ * NE;                 // 32 MB
    short* Wb   = (short*)(part + (size_t)512 * NJ * 512);   // 64 MB
    short* xT   = Wb + (size_t)NJ * NIP * NE * 32;           // 8 MB

    convxT_k<<<(NI * NB) / 256, 256, 0, stream>>>(x, xT);

    // round 0: uniform c = 1/32; converts W -> Wb inline (r3-proven)
    wsum_k<<<NJ * NKC, 128, 0, stream>>>(W, xT, Wb, part);
    rs_k<<<65536 / 512, 512, 0, stream>>>(part, Oacc, out, 0);

    // round 1 (batched fused logits+softmax+weighted-sum)
    fwd_k<<<512, 512, 0, stream>>>(xT, Wb, Oacc, part);
    rs2_k<<<262144 / 512, 512, 0, stream>>>(part, Oacc, out, 1);

    // round 2
    fwd_k<<<512, 512, 0, stream>>>(xT, Wb, Oacc, part);
    rs2_k<<<262144 / 512, 512, 0, stream>>>(part, Oacc, out, 2);
}

// Round 9
// 358.087 us; speedup vs baseline: 1.3820x; 1.0026x over previous
//
#include <hip/hip_runtime.h>
#include <hip/hip_bf16.h>

#define NB 64     // batch
#define NI 2048   // input capsules
#define ND 16     // d_in
#define NJ 32     // output capsules
#define NE 32     // d_out
#define NIP (NI/2)  // i-pairs
#define NKC 64    // round-0 wsum grid kc dimension (64 chunks of 16 ip)
#define NSL NKC   // round-0 partial slices

typedef __attribute__((ext_vector_type(8))) short bfrag;   // 8 bf16 (4 VGPRs)
typedef __attribute__((ext_vector_type(4))) float f32x4;

// two floats -> packed bf16x2 (v_cvt_pk_bf16_f32 on gfx950), RNE
__device__ inline unsigned pk2bf(float a, float b) {
    __hip_bfloat162 h = __float22bfloat162_rn(make_float2(a, b));
    return *reinterpret_cast<unsigned*>(&h);
}

// add value rotated by N within each 16-lane DPP row (row_ror:N)
template <int N>
__device__ inline float rot16_add(float v) {
    int r = __builtin_amdgcn_mov_dpp(__float_as_int(v), 0x120 + N, 0xf, 0xf, false);
    return v + __int_as_float(r);
}

// unpack a dword of 2 bf16, scale by cc, repack (RNE)
__device__ inline unsigned scale_pair(unsigned u, float cc) {
    float f0 = __uint_as_float(u << 16);
    float f1 = __uint_as_float(u & 0xffff0000u);
    return pk2bf(f0 * cc, f1 * cc);
}

// ---------------------------------------------------------------------------
// convxT_k: x fp32 [NB][NI][ND] -> xT bf16 [NI][NB][ND].  (proven)
// ---------------------------------------------------------------------------
__global__ __launch_bounds__(256) void convxT_k(const float* __restrict__ x,
                                                short* __restrict__ xT)
{
    const int T = blockIdx.x * 256 + threadIdx.x;   // NI*NB = 131072
    const int i = T >> 6, b = T & 63;
    const float4* src = reinterpret_cast<const float4*>(
        x + ((size_t)b * NI + i) * ND);
    float4 a0 = src[0], a1 = src[1], a2 = src[2], a3 = src[3];
    bfrag lo, hi;
    unsigned* lu = reinterpret_cast<unsigned*>(&lo);
    unsigned* hu = reinterpret_cast<unsigned*>(&hi);
    lu[0] = pk2bf(a0.x, a0.y); lu[1] = pk2bf(a0.z, a0.w);
    lu[2] = pk2bf(a1.x, a1.y); lu[3] = pk2bf(a1.z, a1.w);
    hu[0] = pk2bf(a2.x, a2.y); hu[1] = pk2bf(a2.z, a2.w);
    hu[2] = pk2bf(a3.x, a3.y); hu[3] = pk2bf(a3.z, a3.w);
    short* dst = xT + ((size_t)i * NB + b) * ND;
    *reinterpret_cast<bfrag*>(dst)     = lo;
    *reinterpret_cast<bfrag*>(dst + 8) = hi;
}

// ---------------------------------------------------------------------------
// fwd_k v3: fused routing round (r8 compute phases, NEW epilogue layout).
// r8 post-mortem: rs2 was ~60us because the reduce axis (ic) sat at 64KB
// stride. Fix at the producer: part[(b*NJ+j)*128 + ic][e32] -- ic INNER,
// so the consumer's reduction input is one contiguous 16KB block per (b,j).
// Phases (unchanged): batched logits -> 1 barrier -> 256-thread softmax ->
// 1 barrier -> c-scaled-A MFMA accumulate.
// ---------------------------------------------------------------------------
__global__ __launch_bounds__(512) void fwd_k(
    const short* __restrict__ xT,     // [NI][NB][ND] bf16
    const short* __restrict__ Wb,     // [NJ][NIP][NE][32] bf16
    const float* __restrict__ Oacc,   // [NB][NJ][NE]
    float* __restrict__ part)         // [NB*NJ][128][32] = 32 MB
{
    const int l    = blockIdx.x;       // 0..511
    const int grp  = l >> 5;           // 16 groups
    const int bb   = (l >> 3) & 3;
    const int ic   = grp * 8 + (l & 7);
    const int b0   = bb * 16;
    const int i0   = ic * 16;
    const int t    = threadIdx.x;
    const int wv   = t >> 6;           // 0..7 -> j-set wv*4..wv*4+3
    const int ln   = t & 63;
    const int m    = ln & 15;
    const int quad = ln >> 4;

    __shared__ float lsm[16][NJ][16];  // [il][j][b16]  32 KB

    // Hoist Oacc fragments for this wave's 4 j's (proven lgsm pattern).
    float O0[4][4], O1[4][4];
#pragma unroll
    for (int jj = 0; jj < 4; ++jj) {
        const int j = wv * 4 + jj;
#pragma unroll
        for (int r = 0; r < 4; ++r) {
            const int b = b0 + quad * 4 + r;
            O0[jj][r] = Oacc[((size_t)b * NJ + j) * NE + m];
            O1[jj][r] = Oacc[((size_t)b * NJ + j) * NE + 16 + m];
        }
    }

    const int  bA  = b0 + m;        // A-operand row (b) this lane supplies
    const bool act = quad < 2;      // quads 0,1 carry k=0..15 (d); 2,3 pad
    const int  d0  = quad * 8;

    // ---- phase 1: ALL logits (no barriers inside -> cross-il ILP) ----
    for (int il = 0; il < 16; ++il) {
        const int i = i0 + il;
        const int ip = i >> 1, isel = i & 1;
        bfrag av = (bfrag)0;
        if (act) {
            av = *reinterpret_cast<const bfrag*>(
                xT + ((size_t)i * NB + bA) * ND + d0);
        }
#pragma unroll
        for (int jj = 0; jj < 4; ++jj) {
            const int j = wv * 4 + jj;
            bfrag bv0 = (bfrag)0, bv1 = (bfrag)0;
            if (act) {
                const short* wp = Wb + (((size_t)j * NIP + ip) * NE + m) * 32
                                     + isel * 16 + d0;
                bv0 = *reinterpret_cast<const bfrag*>(wp);
                bv1 = *reinterpret_cast<const bfrag*>(wp + 16 * 32);
            }
            f32x4 z = {0.f, 0.f, 0.f, 0.f};
            f32x4 U0 = __builtin_amdgcn_mfma_f32_16x16x32_bf16(av, bv0, z, 0, 0, 0);
            f32x4 U1 = __builtin_amdgcn_mfma_f32_16x16x32_bf16(av, bv1, z, 0, 0, 0);

            float v4[4];
#pragma unroll
            for (int r = 0; r < 4; ++r) {
                float v = fmaf(U0[r], O0[jj][r], U1[r] * O1[jj][r]);
                v = rot16_add<1>(v);
                v = rot16_add<2>(v);
                v = rot16_add<4>(v);
                v = rot16_add<8>(v);
                v4[r] = v;
            }
            if (m == 0) {
                *reinterpret_cast<float4*>(&lsm[il][j][quad * 4]) =
                    make_float4(v4[0], v4[1], v4[2], v4[3]);
            }
        }
    }
    __syncthreads();

    // ---- softmax over j: 256 threads, one (il,b) row each ----
    if (t < 256) {
        const int il = t >> 4, b = t & 15;
        float mx = -1e30f;
#pragma unroll
        for (int jx = 0; jx < NJ; ++jx) mx = fmaxf(mx, lsm[il][jx][b]);
        float sum = 0.f;
#pragma unroll
        for (int jx = 0; jx < NJ; ++jx) {
            const float e = __expf(lsm[il][jx][b] - mx);
            lsm[il][jx][b] = e;
            sum += e;
        }
        const float inv = 1.0f / sum;
#pragma unroll
        for (int jx = 0; jx < NJ; ++jx) lsm[il][jx][b] *= inv;
    }
    __syncthreads();

    // ---- phase 2: s[b,j,e] += c * u_hat via c-scaled A (wsum math) ----
    f32x4 acc0[4] = {{0.f,0.f,0.f,0.f},{0.f,0.f,0.f,0.f},
                     {0.f,0.f,0.f,0.f},{0.f,0.f,0.f,0.f}};
    f32x4 acc1[4] = {{0.f,0.f,0.f,0.f},{0.f,0.f,0.f,0.f},
                     {0.f,0.f,0.f,0.f},{0.f,0.f,0.f,0.f}};
    for (int il = 0; il < 16; ++il) {
        const int i = i0 + il;
        const int ip = i >> 1, isel = i & 1;
        uint4 xr = {0u, 0u, 0u, 0u};
        if (act) {
            xr = *reinterpret_cast<const uint4*>(
                xT + ((size_t)i * NB + bA) * ND + d0);
        }
#pragma unroll
        for (int jj = 0; jj < 4; ++jj) {
            const int j = wv * 4 + jj;
            const float cv = lsm[il][j][m];    // c[j][i][b=bA] (broadcast)
            bfrag av2;
            unsigned* au = reinterpret_cast<unsigned*>(&av2);
            au[0] = scale_pair(xr.x, cv);
            au[1] = scale_pair(xr.y, cv);
            au[2] = scale_pair(xr.z, cv);
            au[3] = scale_pair(xr.w, cv);
            bfrag bv0 = (bfrag)0, bv1 = (bfrag)0;
            if (act) {
                const short* wp = Wb + (((size_t)j * NIP + ip) * NE + m) * 32
                                     + isel * 16 + d0;
                bv0 = *reinterpret_cast<const bfrag*>(wp);
                bv1 = *reinterpret_cast<const bfrag*>(wp + 16 * 32);
            }
            acc0[jj] = __builtin_amdgcn_mfma_f32_16x16x32_bf16(av2, bv0, acc0[jj], 0, 0, 0);
            acc1[jj] = __builtin_amdgcn_mfma_f32_16x16x32_bf16(av2, bv1, acc1[jj], 0, 0, 0);
        }
    }

    // ---- epilogue: ic-INNER layout part[(b*NJ+j)*128 + ic][e32] ----
    // Each (thread, jj, r) owns a unique (b, j, e/e+16) -> scalar stores;
    // 16 lanes (m=0..15) write 64B contiguous per (jj,r) group.
#pragma unroll
    for (int jj = 0; jj < 4; ++jj) {
        const int j = wv * 4 + jj;
#pragma unroll
        for (int r = 0; r < 4; ++r) {
            const int bg = b0 + quad * 4 + r;
            float* p = part + (((size_t)(bg * NJ + j) * 128) + ic) * 32;
            p[m]      = acc0[jj][r];
            p[m + 16] = acc1[jj][r];
        }
    }
}

// ---------------------------------------------------------------------------
// rs2_k v3: reduce fwd partials + squash. One WAVE per (b,j): the wave's
// entire input is a contiguous 16KB block ([128 ic][32 e] floats) -> 16
// coalesced f32x4 loads per lane (independent -> MLP), then shuffle
// reduction: xor 8/16/32 sums the 8 ic-subsets per e-quad; xor 1/2/4 sums
// the squared-norm across e-quads. Lanes 0..7 write one f32x4 each.
// mode 1: Oacc += squash(s);  mode 2: out = squash(s).
// ---------------------------------------------------------------------------
__global__ __launch_bounds__(512) void rs2_k(
    const float* __restrict__ part,      // [NB*NJ][128][32]
    float* __restrict__ Oacc,            // [NB][NJ][NE]
    float* __restrict__ out,             // [NB][NJ][NE]
    int mode)
{
    const int gt = blockIdx.x * 512 + threadIdx.x;
    const int w  = gt >> 6;              // wave id 0..2047 = (b*32+j)
    const int ln = gt & 63;

    const float* p = part + (size_t)w * 4096;
    f32x4 acc = {0.f, 0.f, 0.f, 0.f};
#pragma unroll
    for (int k = 0; k < 16; ++k) {
        const f32x4 v = *reinterpret_cast<const f32x4*>(p + k * 256 + ln * 4);
        acc += v;
    }
    // lane ln holds partial sums for e = (ln&7)*4..+3 over ic = {k*8 + (ln>>3)}
#pragma unroll
    for (int i = 0; i < 4; ++i) {
        acc[i] += __shfl_xor(acc[i], 8);
        acc[i] += __shfl_xor(acc[i], 16);
        acc[i] += __shfl_xor(acc[i], 32);
    }
    // now every lane holds the full ic-sum for its e-quad (ln&7)
    float q = acc[0]*acc[0] + acc[1]*acc[1] + acc[2]*acc[2] + acc[3]*acc[3];
    q += __shfl_xor(q, 1);
    q += __shfl_xor(q, 2);
    q += __shfl_xor(q, 4);   // full sum of squares over all 32 e

    const float scale = q / ((1.0f + q) * sqrtf(q + 1e-7f));
    if (ln < 8) {
        float* op = (mode == 2 ? out : Oacc) + (size_t)w * NE + ln * 4;
        f32x4 o;
        o[0] = scale * acc[0]; o[1] = scale * acc[1];
        o[2] = scale * acc[2]; o[3] = scale * acc[3];
        if (mode == 1) {
            const f32x4 prev = *reinterpret_cast<const f32x4*>(op);
            o += prev;
        }
        *reinterpret_cast<f32x4*>(op) = o;
    }
}

// ---------------------------------------------------------------------------
// wsum_k: round-0 only (uniform c=1/32), fuses W fp32 -> Wb bf16 conversion.
// r3-PROVEN 8-stage named-variable pipeline (NKC=64), R0 specialized.
// ---------------------------------------------------------------------------

#define WS_LOAD(P, itv)                                                        \
    {   const int ip_ = ip0 + (itv);                                           \
        const int ia_ = ip_ * 2 + isel;                                        \
        {                                                                      \
            const float* wp_ = Wsrc + (((size_t)j * NI + ia_) * NE + m) * ND + d0; \
            P##w0 = *reinterpret_cast<const float4*>(wp_);                     \
            P##w1 = *reinterpret_cast<const float4*>(wp_ + 4);                 \
            P##w2 = *reinterpret_cast<const float4*>(wp_ + 16 * ND);           \
            P##w3 = *reinterpret_cast<const float4*>(wp_ + 16 * ND + 4);       \
        }                                                                      \
        const short* xp_ = xT + ((size_t)ia_ * NB + m) * ND + d0;              \
        P##x0 = *reinterpret_cast<const uint4*>(xp_);                          \
        P##x1 = *reinterpret_cast<const uint4*>(xp_ + 16 * ND);                \
        P##x2 = *reinterpret_cast<const uint4*>(xp_ + 32 * ND);                \
        P##x3 = *reinterpret_cast<const uint4*>(xp_ + 48 * ND);                \
    }

#define WS_MT(XV, A0, A1)                                                      \
    {   const float cc_ = 1.0f / NJ;                                           \
        bfrag av_;                                                             \
        unsigned* au_ = reinterpret_cast<unsigned*>(&av_);                     \
        au_[0] = scale_pair((XV).x, cc_); au_[1] = scale_pair((XV).y, cc_);    \
        au_[2] = scale_pair((XV).z, cc_); au_[3] = scale_pair((XV).w, cc_);    \
        A0 = __builtin_amdgcn_mfma_f32_16x16x32_bf16(av_, bv0_, A0, 0, 0, 0);  \
        A1 = __builtin_amdgcn_mfma_f32_16x16x32_bf16(av_, bv1_, A1, 0, 0, 0);  \
    }

#define WS_COMPUTE(P, itv)                                                     \
    {   bfrag bv0_, bv1_;                                                      \
        {                                                                      \
            unsigned* b0_ = reinterpret_cast<unsigned*>(&bv0_);                \
            unsigned* b1_ = reinterpret_cast<unsigned*>(&bv1_);                \
            b0_[0] = pk2bf(P##w0.x, P##w0.y); b0_[1] = pk2bf(P##w0.z, P##w0.w);\
            b0_[2] = pk2bf(P##w1.x, P##w1.y); b0_[3] = pk2bf(P##w1.z, P##w1.w);\
            b1_[0] = pk2bf(P##w2.x, P##w2.y); b1_[1] = pk2bf(P##w2.z, P##w2.w);\
            b1_[2] = pk2bf(P##w3.x, P##w3.y); b1_[3] = pk2bf(P##w3.z, P##w3.w);\
            short* wd_ = Wb + (((size_t)j * NIP + (ip0 + (itv))) * NE + m) * 32 + quad * 8; \
            *reinterpret_cast<bfrag*>(wd_)       = bv0_;                       \
            *reinterpret_cast<bfrag*>(wd_ + 512) = bv1_;                       \
        }                                                                      \
        WS_MT(P##x0, a00, a01)                                                 \
        WS_MT(P##x1, a10, a11)                                                 \
        WS_MT(P##x2, a20, a21)                                                 \
        WS_MT(P##x3, a30, a31)                                                 \
    }

__global__ __launch_bounds__(128) void wsum_k(
    const float* __restrict__ Wsrc,   // [NJ][NI][NE][ND] fp32
    const short* __restrict__ xT,     // [NI][NB][ND] bf16
    short* __restrict__ Wb,           // [NJ][NIP][NE][32] bf16 (out)
    float* __restrict__ partial)      // [NSL][NJ][2048]
{
    const int l    = blockIdx.x;       // 0..2047
    const int x    = l & 7;            // XCD slot
    const int r    = l >> 3;           // 0..255
    const int j    = r & 31;
    const int kc   = x * 8 + (r >> 5); // 0..63
    const int t    = threadIdx.x;      // 0..127
    const int wv   = t >> 6;           // 0..1
    const int ln   = t & 63;
    const int m    = ln & 15;
    const int quad = ln >> 4;
    const int isel = quad >> 1;
    const int d0   = (quad & 1) * 8;
    const int ip0  = kc * 16 + wv * 8;

    __shared__ float red[2][2048];     // 16 KB

    f32x4 a00 = {0.f,0.f,0.f,0.f}, a01 = {0.f,0.f,0.f,0.f};
    f32x4 a10 = {0.f,0.f,0.f,0.f}, a11 = {0.f,0.f,0.f,0.f};
    f32x4 a20 = {0.f,0.f,0.f,0.f}, a21 = {0.f,0.f,0.f,0.f};
    f32x4 a30 = {0.f,0.f,0.f,0.f}, a31 = {0.f,0.f,0.f,0.f};

    float4 Aw0, Aw1, Aw2, Aw3, Bw0, Bw1, Bw2, Bw3;
    uint4  Ax0, Ax1, Ax2, Ax3, Bx0, Bx1, Bx2, Bx3;

    WS_LOAD(A, 0)
    WS_LOAD(B, 1)
    WS_COMPUTE(A, 0)
    WS_LOAD(A, 2)
    WS_COMPUTE(B, 1)
    WS_LOAD(B, 3)
    WS_COMPUTE(A, 2)
    WS_LOAD(A, 4)
    WS_COMPUTE(B, 3)
    WS_LOAD(B, 5)
    WS_COMPUTE(A, 4)
    WS_LOAD(A, 6)
    WS_COMPUTE(B, 5)
    WS_LOAD(B, 7)
    WS_COMPUTE(A, 6)
    WS_COMPUTE(B, 7)

    float* rb = &red[wv][0];
    *reinterpret_cast<f32x4*>(rb + 0 * 256 + ln * 4) = a00;
    *reinterpret_cast<f32x4*>(rb + 1 * 256 + ln * 4) = a01;
    *reinterpret_cast<f32x4*>(rb + 2 * 256 + ln * 4) = a10;
    *reinterpret_cast<f32x4*>(rb + 3 * 256 + ln * 4) = a11;
    *reinterpret_cast<f32x4*>(rb + 4 * 256 + ln * 4) = a20;
    *reinterpret_cast<f32x4*>(rb + 5 * 256 + ln * 4) = a21;
    *reinterpret_cast<f32x4*>(rb + 6 * 256 + ln * 4) = a30;
    *reinterpret_cast<f32x4*>(rb + 7 * 256 + ln * 4) = a31;
    __syncthreads();

    float* pb = partial + ((size_t)kc * NJ + j) * 2048;
#pragma unroll
    for (int k = 0; k < 4; ++k) {
        const int g = k * 512 + t * 4;
        f32x4 s = *reinterpret_cast<const f32x4*>(&red[0][g]);
        s += *reinterpret_cast<const f32x4*>(&red[1][g]);
        *reinterpret_cast<f32x4*>(pb + g) = s;
    }
}

// ---------------------------------------------------------------------------
// rs_k: round-0 reduce (wsum flat layout, NSL=64) + squash. mode 0 only.
// ---------------------------------------------------------------------------
__global__ __launch_bounds__(512) void rs_k(
    const float* __restrict__ partial,   // [NSL][NJ][2048]
    float* __restrict__ Oacc,            // [NB][NJ][NE]
    float* __restrict__ out,             // [NB][NJ][NE]
    int mode)
{
    const int G    = blockIdx.x * 512 + threadIdx.x;   // 0..65535
    const int j    = G >> 11;
    const int g    = G & 2047;
    const int group = g >> 8;           // 0..7 = mt*2+nt
    const int mt   = group >> 1;
    const int nt   = group & 1;
    const int lnn  = (g >> 2) & 63;
    const int m    = lnn & 15;
    const int quad = lnn >> 4;
    const int r    = g & 3;
    const int b    = mt * 16 + quad * 4 + r;
    const int e    = nt * 16 + m;

    float sum = 0.f;
#pragma unroll 8
    for (int sl = 0; sl < NSL; ++sl)
        sum += partial[((size_t)sl * NJ + j) * 2048 + g];

    __shared__ float lds[512];
    const int row = quad * 4 + r;        // 0..15
    lds[row * 32 + e] = sum;
    __syncthreads();
    const float* rp = &lds[row * 32];
    float p = 0.f;
#pragma unroll
    for (int ee = 0; ee < 32; ++ee) p = fmaf(rp[ee], rp[ee], p);

    const float scale = p / ((1.0f + p) * sqrtf(p + 1e-7f));
    const float o = scale * sum;
    const size_t off = ((size_t)b * NJ + j) * NE + e;
    if (mode == 2)      out[off]  = o;
    else if (mode == 1) Oacc[off] += o;
    else                Oacc[off] = o;
}

extern "C" void kernel_launch(void* const* d_in, const int* in_sizes, int n_in,
                              void* d_out, int out_size, void* d_ws, size_t ws_size,
                              hipStream_t stream)
{
    (void)in_sizes; (void)n_in; (void)out_size; (void)ws_size;
    const float* x = (const float*)d_in[0];   // [64][2048][16]
    const float* W = (const float*)d_in[1];   // [32][2048][32][16]
    float* out = (float*)d_out;               // [64][32][32]

    // ws layout (~104 MB of 512 MB). part region (32 MB) shared by the
    // round-0 flat layout (16 MB) and fwd's (b,j)-outer layout (sequential).
    float* Oacc = (float*)d_ws;                        // 256 KB
    float* part = Oacc + NB * NJ * NE;                 // 32 MB
    short* Wb   = (short*)(part + (size_t)NB * NJ * 128 * 32);  // 64 MB
    short* xT   = Wb + (size_t)NJ * NIP * NE * 32;              // 8 MB

    convxT_k<<<(NI * NB) / 256, 256, 0, stream>>>(x, xT);

    // round 0: uniform c = 1/32; converts W -> Wb inline (r3-proven)
    wsum_k<<<NJ * NKC, 128, 0, stream>>>(W, xT, Wb, part);
    rs_k<<<65536 / 512, 512, 0, stream>>>(part, Oacc, out, 0);

    // round 1 (batched fused logits+softmax+weighted-sum)
    fwd_k<<<512, 512, 0, stream>>>(xT, Wb, Oacc, part);
    rs2_k<<<256, 512, 0, stream>>>(part, Oacc, out, 1);

    // round 2
    fwd_k<<<512, 512, 0, stream>>>(xT, Wb, Oacc, part);
    rs2_k<<<256, 512, 0, stream>>>(part, Oacc, out, 2);
}